// Round 5
// baseline (1042.153 us; speedup 1.0000x reference)
//
#include <hip/hip_runtime.h>
#include <hip/hip_bf16.h>

typedef __bf16 bf16;
typedef __bf16 bf16x8 __attribute__((ext_vector_type(8)));
typedef float f32x4 __attribute__((ext_vector_type(4)));

#define B_    2
#define L_    2048
#define DM_   2048
#define DI_   4096
#define NST   64
#define PD    64
#define NH    64
#define CONV_ 4224
#define XBCD_ 4288            // CONV_ + NH  (xBC + dt columns)
#define PROJ_ 8384
#define BL_   (B_ * L_)
#define EPS_  1e-6f

// ---------------------------------------------------------------- reductions
__device__ __forceinline__ float block_reduce_sum_256(float v) {
  #pragma unroll
  for (int m = 32; m; m >>= 1) v += __shfl_xor(v, m, 64);
  __shared__ float sred[4];
  int w = threadIdx.x >> 6;
  if ((threadIdx.x & 63) == 0) sred[w] = v;
  __syncthreads();
  return sred[0] + sred[1] + sred[2] + sred[3];
}

__device__ __forceinline__ float silu_f(float x) {
  return x / (1.0f + expf(-x));
}

// ---------------------------------------------------------------- RMSNorm in
// u fp32, ln_w fp32 -> hs bf16
__global__ __launch_bounds__(256) void rmsnorm_in_kernel(
    const float* __restrict__ u, const float* __restrict__ w, bf16* __restrict__ hs) {
  int row = blockIdx.x;
  const float* x = u + (size_t)row * DM_;
  int base = threadIdx.x * 8;
  f32x4 v0 = *(const f32x4*)(x + base);
  f32x4 v1 = *(const f32x4*)(x + base + 4);
  float xv[8], ss = 0.f;
  #pragma unroll
  for (int i = 0; i < 4; i++) { xv[i] = v0[i]; xv[4 + i] = v1[i]; }
  #pragma unroll
  for (int i = 0; i < 8; i++) ss += xv[i] * xv[i];
  ss = block_reduce_sum_256(ss);
  float r = rsqrtf(ss / (float)DM_ + EPS_);
  f32x4 w0 = *(const f32x4*)(w + base);
  f32x4 w1 = *(const f32x4*)(w + base + 4);
  bf16x8 o;
  #pragma unroll
  for (int i = 0; i < 4; i++) { o[i] = (bf16)(w0[i] * xv[i] * r); o[4 + i] = (bf16)(w1[i] * xv[4 + i] * r); }
  *(bf16x8*)(hs + (size_t)row * DM_ + base) = o;
}

// ---------------------------------------------------------------- NT GEMM
// C[i][j] = sum_k A[i][k] * Bm[j][k]
// A: bf16, M x K rows stride lda.  Bm: FP32, N x K (ldb=K), converted to bf16
// during LDS staging.  Output: bf16 or fp32 per OUT_F32.  resid (fp32, stride
// ldc) added when non-null.
template <bool OUT_F32>
__global__ __launch_bounds__(256) void gemm_nt_kernel(
    const bf16* __restrict__ A, int lda,
    const float* __restrict__ Bm,
    void* __restrict__ Cout, int ldc, const float* __restrict__ resid,
    int N, int K) {
  __shared__ bf16 As[128][72];   // +8 pad keeps 16B align, breaks stride conflicts
  __shared__ bf16 Bs[128][72];
  int bm = blockIdx.y, bn = blockIdx.x;
  int m0 = bm * 128, n0 = bn * 128;
  int tid  = threadIdx.x;
  int wave = tid >> 6, lane = tid & 63;
  int wm = (wave >> 1) * 64, wn = (wave & 1) * 64;
  int lm = lane & 15, lk = (lane >> 4) * 8;
  f32x4 acc[4][4] = {};
  for (int k0 = 0; k0 < K; k0 += 64) {
    #pragma unroll
    for (int i = 0; i < 4; i++) {
      int c = tid + i * 256;
      int row = c >> 3, col8 = c & 7;
      const bf16* ga = A + (size_t)(m0 + row) * lda + k0 + col8 * 8;
      *(bf16x8*)&As[row][col8 * 8] = *(const bf16x8*)ga;
      int jr = n0 + row; if (jr >= N) jr = N - 1;       // clamp (tail tile)
      const float* gb = Bm + (size_t)jr * K + k0 + col8 * 8;
      f32x4 b0 = *(const f32x4*)gb;
      f32x4 b1 = *(const f32x4*)(gb + 4);
      bf16x8 bb;
      #pragma unroll
      for (int q = 0; q < 4; q++) { bb[q] = (bf16)b0[q]; bb[4 + q] = (bf16)b1[q]; }
      *(bf16x8*)&Bs[row][col8 * 8] = bb;
    }
    __syncthreads();
    #pragma unroll
    for (int ks = 0; ks < 64; ks += 32) {
      bf16x8 af[4], bfr[4];
      #pragma unroll
      for (int i = 0; i < 4; i++) af[i]  = *(bf16x8*)&As[wm + i * 16 + lm][ks + lk];
      #pragma unroll
      for (int j = 0; j < 4; j++) bfr[j] = *(bf16x8*)&Bs[wn + j * 16 + lm][ks + lk];
      #pragma unroll
      for (int i = 0; i < 4; i++)
        #pragma unroll
        for (int j = 0; j < 4; j++)
          acc[i][j] = __builtin_amdgcn_mfma_f32_16x16x32_bf16(af[i], bfr[j], acc[i][j], 0, 0, 0);
    }
    __syncthreads();
  }
  // epilogue: C/D layout col=lane&15, row=(lane>>4)*4+reg   [m89-verified]
  int r0 = m0 + wm + (lane >> 4) * 4;
  #pragma unroll
  for (int i = 0; i < 4; i++) {
    #pragma unroll
    for (int j = 0; j < 4; j++) {
      int col = n0 + wn + j * 16 + (lane & 15);
      if (col < N) {
        #pragma unroll
        for (int r = 0; r < 4; r++) {
          int row = r0 + i * 16 + r;
          size_t idx = (size_t)row * ldc + col;
          float v = acc[i][j][r];
          if (resid) v += resid[idx];
          if (OUT_F32) ((float*)Cout)[idx] = v;
          else         ((bf16*)Cout)[idx]  = (bf16)v;
        }
      }
    }
  }
}

// ---------------------------------------------------------------- conv1d+SiLU
// xbcdt: BL x XBCD_ bf16 (cols 0..CONV_-1 are xBC); cw/cb fp32; writes xc bf16
__global__ __launch_bounds__(256) void conv_silu_kernel(
    const bf16* __restrict__ xbcdt, const float* __restrict__ cw,
    const float* __restrict__ cb, bf16* __restrict__ xc) {
  int idx = blockIdx.x * 256 + threadIdx.x;      // over BL * CONV/8
  int nC8 = CONV_ / 8;
  if (idx >= BL_ * nC8) return;
  int c8 = idx % nC8, t = idx / nC8;
  int l = t % L_;
  int c = c8 * 8;
  float acc[8];
  f32x4 bv0 = *(const f32x4*)(cb + c);
  f32x4 bv1 = *(const f32x4*)(cb + c + 4);
  #pragma unroll
  for (int q = 0; q < 4; q++) { acc[q] = bv0[q]; acc[4 + q] = bv1[q]; }
  #pragma unroll
  for (int k = 0; k < 4; k++) {
    int ls = l + k - 3;
    if (ls >= 0) {
      const bf16* xp = xbcdt + (size_t)(t + k - 3) * XBCD_ + c;
      bf16x8 xv = *(const bf16x8*)xp;
      f32x4 wv0 = *(const f32x4*)(cw + k * CONV_ + c);
      f32x4 wv1 = *(const f32x4*)(cw + k * CONV_ + c + 4);
      #pragma unroll
      for (int q = 0; q < 4; q++) { acc[q] += (float)xv[q] * wv0[q]; acc[4 + q] += (float)xv[4 + q] * wv1[q]; }
    }
  }
  bf16x8 o;
  #pragma unroll
  for (int q = 0; q < 8; q++) o[q] = (bf16)silu_f(acc[q]);
  *(bf16x8*)(xc + (size_t)t * CONV_ + c) = o;
}

// ---------------------------------------------------------------- dt / dA
__global__ __launch_bounds__(256) void dt_da_kernel(
    const bf16* __restrict__ xbcdt, const float* __restrict__ dt_bias,
    const float* __restrict__ A_log, float* __restrict__ dt, float* __restrict__ dA) {
  int idx = blockIdx.x * 256 + threadIdx.x;      // over BL*NH
  if (idx >= BL_ * NH) return;
  int h = idx % NH, t = idx / NH;
  float raw = (float)xbcdt[(size_t)t * XBCD_ + CONV_ + h] + dt_bias[h];
  float dtv = (raw > 20.f) ? raw : log1pf(expf(raw));
  dt[idx] = dtv;
  dA[idx] = expf(-expf(A_log[h]) * dtv);
}

// ---------------------------------------------------------------- SSM scan
// grid 256: (b, h, p-half of 32).  Thread: pl = tid/8 (32 p's), nc = tid%8 (8 n's).
// State h[p][n] in regs (8 fp32/thread). Chunk-64 LDS staging.
// Fuses dt*x and the D*x skip term; writes (y + D*x) bf16 OVER the x-region
// of xc (cells staged into LDS before overwrite; blocks touch disjoint cells).
__global__ __launch_bounds__(256) void ssm_scan_kernel(
    bf16* __restrict__ xc, const float* __restrict__ dt,
    const float* __restrict__ dA, const float* __restrict__ Dp) {
  __shared__ float xs[64][32];    // raw x (post conv+silu)
  __shared__ float Bs[64][64];
  __shared__ float Cs[64][64];
  __shared__ float dAs[64];
  __shared__ float dts[64];
  __shared__ float ys[64][32];
  int bi = blockIdx.x;
  int b = bi >> 7, rem = bi & 127;
  int h = rem >> 1, p0 = (rem & 1) * 32;
  int tid = threadIdx.x;
  int nc = tid & 7, pl = tid >> 3;
  float Dv = Dp[h];
  float hst[8] = {};
  size_t rowbase = (size_t)b * L_;
  for (int l0 = 0; l0 < L_; l0 += 64) {
    #pragma unroll
    for (int i = 0; i < 8; i++) {
      int idx = tid + i * 256; int s = idx >> 5, pp = idx & 31;
      size_t row = rowbase + l0 + s;
      xs[s][pp] = (float)xc[row * CONV_ + h * PD + p0 + pp];
    }
    #pragma unroll
    for (int i = 0; i < 2; i++) {
      int c = tid + i * 256; int s = c >> 3, n8 = (c & 7) * 8;
      size_t row = rowbase + l0 + s;
      bf16x8 bv = *(const bf16x8*)(xc + row * CONV_ + DI_ + n8);
      bf16x8 cv = *(const bf16x8*)(xc + row * CONV_ + DI_ + NST + n8);
      #pragma unroll
      for (int q = 0; q < 8; q++) { Bs[s][n8 + q] = (float)bv[q]; Cs[s][n8 + q] = (float)cv[q]; }
    }
    if (tid < 64) {
      size_t row = rowbase + l0 + tid;
      dAs[tid] = dA[row * NH + h];
      dts[tid] = dt[row * NH + h];
    }
    __syncthreads();                    // barrier A
    for (int s = 0; s < 64; s++) {
      float dAv = dAs[s];
      float xv  = xs[s][pl];
      float dtx = dts[s] * xv;
      f32x4 Bv0 = *(f32x4*)&Bs[s][nc * 8];
      f32x4 Bv1 = *(f32x4*)&Bs[s][nc * 8 + 4];
      f32x4 Cv0 = *(f32x4*)&Cs[s][nc * 8];
      f32x4 Cv1 = *(f32x4*)&Cs[s][nc * 8 + 4];
      float yp = 0.f;
      #pragma unroll
      for (int q = 0; q < 4; q++) { hst[q]     = dAv * hst[q]     + dtx * Bv0[q]; yp += hst[q]     * Cv0[q]; }
      #pragma unroll
      for (int q = 0; q < 4; q++) { hst[4 + q] = dAv * hst[4 + q] + dtx * Bv1[q]; yp += hst[4 + q] * Cv1[q]; }
      yp += __shfl_xor(yp, 1, 64);
      yp += __shfl_xor(yp, 2, 64);
      yp += __shfl_xor(yp, 4, 64);
      if (nc == 0) ys[s][pl] = yp + Dv * xv;
    }
    __syncthreads();                    // barrier B
    #pragma unroll
    for (int i = 0; i < 8; i++) {
      int idx = tid + i * 256; int s = idx >> 5, pp = idx & 31;
      xc[(rowbase + l0 + s) * CONV_ + h * PD + p0 + pp] = (bf16)ys[s][pp];
    }
    // barrier A of next iter protects ys reads vs next scan-loop writes
  }
}

// ---------------------------------------------------------------- gated RMSNorm
// y (=ssm out + D*x) from x-region of xc; z from zbuf; nw fp32; in-place zbuf.
__global__ __launch_bounds__(256) void gated_norm_kernel(
    const bf16* __restrict__ xc, bf16* __restrict__ zbuf,
    const float* __restrict__ nw) {
  int t = blockIdx.x;
  int base = threadIdx.x * 16;
  const bf16* yr = xc + (size_t)t * CONV_;
  bf16* zr = zbuf + (size_t)t * DI_;
  float tv[16], ss = 0.f;
  #pragma unroll
  for (int i8 = 0; i8 < 2; i8++) {
    bf16x8 yv = *(const bf16x8*)(yr + base + i8 * 8);
    bf16x8 zv = *(const bf16x8*)(zr + base + i8 * 8);
    #pragma unroll
    for (int q = 0; q < 8; q++) {
      float tt = (float)yv[q] * silu_f((float)zv[q]);
      tv[i8 * 8 + q] = tt;
      ss += tt * tt;
    }
  }
  ss = block_reduce_sum_256(ss);
  float r = rsqrtf(ss / (float)DI_ + EPS_);
  #pragma unroll
  for (int i8 = 0; i8 < 2; i8++) {
    f32x4 w0 = *(const f32x4*)(nw + base + i8 * 8);
    f32x4 w1 = *(const f32x4*)(nw + base + i8 * 8 + 4);
    bf16x8 o;
    #pragma unroll
    for (int q = 0; q < 4; q++) {
      o[q]     = (bf16)(w0[q] * tv[i8 * 8 + q] * r);
      o[4 + q] = (bf16)(w1[q] * tv[i8 * 8 + 4 + q] * r);
    }
    *(bf16x8*)(zr + base + i8 * 8) = o;            // in-place
  }
}

// ---------------------------------------------------------------- ws diagnostic
__global__ void ws_report_kernel(float* out, float ws_mb) {
  if (blockIdx.x == 0 && threadIdx.x == 0) out[0] = ws_mb;
}

// ---------------------------------------------------------------- launch
extern "C" void kernel_launch(void* const* d_in, const int* in_sizes, int n_in,
                              void* d_out, int out_size, void* d_ws, size_t ws_size,
                              hipStream_t stream) {
  const float* u        = (const float*)d_in[0];
  const float* ln_w     = (const float*)d_in[1];
  const float* in_proj  = (const float*)d_in[2];
  const float* conv_w   = (const float*)d_in[3];
  const float* conv_b   = (const float*)d_in[4];
  const float* dt_bias  = (const float*)d_in[5];
  const float* A_log    = (const float*)d_in[6];
  const float* Dp       = (const float*)d_in[7];
  const float* norm_w   = (const float*)d_in[8];
  const float* out_proj = (const float*)d_in[9];
  float* out = (float*)d_out;

  // d_out doubles as scratch for hs (16.8 MB bf16 inside the 33.5 MB fp32
  // out buffer; dead before the final GEMM writes out).
  bf16* hs = (bf16*)d_out;

  char* ws = (char*)d_ws;
  size_t off = 0;
  auto alloc = [&](size_t bytes) { char* p = ws + off; off = (off + bytes + 255) & ~(size_t)255; return p; };
  float* dt   = (float*)alloc((size_t)BL_ * NH * 4);          //  1.05 MB
  float* dA   = (float*)alloc((size_t)BL_ * NH * 4);          //  1.05 MB
  bf16*  shbuf= (bf16*)alloc((size_t)BL_ * XBCD_ * 2);        // 35.1 MB (xbcdt, later zbuf)
  bf16*  xc   = (bf16*)alloc((size_t)BL_ * CONV_ * 2);        // 34.6 MB
  size_t need = off;                                          // ~71.9 MB

  if (ws_size < need) {
    ws_report_kernel<<<1, 64, 0, stream>>>(out, (float)(ws_size >> 20));
    return;
  }

  bf16* xbcdt = shbuf;          // BL x XBCD_ (phase 1)
  bf16* zbuf  = shbuf;          // BL x DI_   (phase 2, after xbcdt dead)

  rmsnorm_in_kernel<<<BL_, 256, 0, stream>>>(u, ln_w, hs);
  // xBC+dt part of in_proj (rows DI_..PROJ_-1)
  gemm_nt_kernel<false><<<dim3((XBCD_ + 127) / 128, BL_ / 128), 256, 0, stream>>>(
      hs, DM_, in_proj + (size_t)DI_ * DM_, xbcdt, XBCD_, nullptr, XBCD_, DM_);
  conv_silu_kernel<<<(BL_ * (CONV_ / 8) + 255) / 256, 256, 0, stream>>>(
      xbcdt, conv_w, conv_b, xc);
  dt_da_kernel<<<(BL_ * NH + 255) / 256, 256, 0, stream>>>(
      xbcdt, dt_bias, A_log, dt, dA);
  // z part of in_proj (rows 0..DI_-1) — overwrites shbuf after conv/dt_da consumed it
  gemm_nt_kernel<false><<<dim3(DI_ / 128, BL_ / 128), 256, 0, stream>>>(
      hs, DM_, in_proj, zbuf, DI_, nullptr, DI_, DM_);
  ssm_scan_kernel<<<256, 256, 0, stream>>>(xc, dt, dA, Dp);
  gated_norm_kernel<<<BL_, 256, 0, stream>>>(xc, zbuf, norm_w);
  gemm_nt_kernel<true><<<dim3(DM_ / 128, BL_ / 128), 256, 0, stream>>>(
      zbuf, DI_, out_proj, out, DM_, u, DM_, DI_);
}

// Round 6
// 974.738 us; speedup vs baseline: 1.0692x; 1.0692x over previous
//
#include <hip/hip_runtime.h>
#include <hip/hip_bf16.h>

typedef __bf16 bf16;
typedef __bf16 bf16x8 __attribute__((ext_vector_type(8)));
typedef float f32x4 __attribute__((ext_vector_type(4)));

#define B_    2
#define L_    2048
#define DM_   2048
#define DI_   4096
#define NST   64
#define PD    64
#define NH    64
#define CONV_ 4224
#define XBCD_ 4288            // CONV_ + NH  (xBC + dt columns)
#define PROJ_ 8384
#define BL_   (B_ * L_)
#define NCHUNK 32             // L_ / 64
#define EPS_  1e-6f

// ---------------------------------------------------------------- reductions
__device__ __forceinline__ float block_reduce_sum_256(float v) {
  #pragma unroll
  for (int m = 32; m; m >>= 1) v += __shfl_xor(v, m, 64);
  __shared__ float sred[4];
  int w = threadIdx.x >> 6;
  if ((threadIdx.x & 63) == 0) sred[w] = v;
  __syncthreads();
  return sred[0] + sred[1] + sred[2] + sred[3];
}

__device__ __forceinline__ float silu_f(float x) {
  return x / (1.0f + expf(-x));
}

// ---------------------------------------------------------------- RMSNorm in
__global__ __launch_bounds__(256) void rmsnorm_in_kernel(
    const float* __restrict__ u, const float* __restrict__ w, bf16* __restrict__ hs) {
  int row = blockIdx.x;
  const float* x = u + (size_t)row * DM_;
  int base = threadIdx.x * 8;
  f32x4 v0 = *(const f32x4*)(x + base);
  f32x4 v1 = *(const f32x4*)(x + base + 4);
  float xv[8], ss = 0.f;
  #pragma unroll
  for (int i = 0; i < 4; i++) { xv[i] = v0[i]; xv[4 + i] = v1[i]; }
  #pragma unroll
  for (int i = 0; i < 8; i++) ss += xv[i] * xv[i];
  ss = block_reduce_sum_256(ss);
  float r = rsqrtf(ss / (float)DM_ + EPS_);
  f32x4 w0 = *(const f32x4*)(w + base);
  f32x4 w1 = *(const f32x4*)(w + base + 4);
  bf16x8 o;
  #pragma unroll
  for (int i = 0; i < 4; i++) { o[i] = (bf16)(w0[i] * xv[i] * r); o[4 + i] = (bf16)(w1[i] * xv[4 + i] * r); }
  *(bf16x8*)(hs + (size_t)row * DM_ + base) = o;
}

// ---------------------------------------------------------------- NT GEMM
template <bool OUT_F32>
__global__ __launch_bounds__(256) void gemm_nt_kernel(
    const bf16* __restrict__ A, int lda,
    const float* __restrict__ Bm,
    void* __restrict__ Cout, int ldc, const float* __restrict__ resid,
    int N, int K) {
  __shared__ bf16 As[128][72];
  __shared__ bf16 Bs[128][72];
  int bm = blockIdx.y, bn = blockIdx.x;
  int m0 = bm * 128, n0 = bn * 128;
  int tid  = threadIdx.x;
  int wave = tid >> 6, lane = tid & 63;
  int wm = (wave >> 1) * 64, wn = (wave & 1) * 64;
  int lm = lane & 15, lk = (lane >> 4) * 8;
  f32x4 acc[4][4] = {};
  for (int k0 = 0; k0 < K; k0 += 64) {
    #pragma unroll
    for (int i = 0; i < 4; i++) {
      int c = tid + i * 256;
      int row = c >> 3, col8 = c & 7;
      const bf16* ga = A + (size_t)(m0 + row) * lda + k0 + col8 * 8;
      *(bf16x8*)&As[row][col8 * 8] = *(const bf16x8*)ga;
      int jr = n0 + row; if (jr >= N) jr = N - 1;       // clamp (tail tile)
      const float* gb = Bm + (size_t)jr * K + k0 + col8 * 8;
      f32x4 b0 = *(const f32x4*)gb;
      f32x4 b1 = *(const f32x4*)(gb + 4);
      bf16x8 bb;
      #pragma unroll
      for (int q = 0; q < 4; q++) { bb[q] = (bf16)b0[q]; bb[4 + q] = (bf16)b1[q]; }
      *(bf16x8*)&Bs[row][col8 * 8] = bb;
    }
    __syncthreads();
    #pragma unroll
    for (int ks = 0; ks < 64; ks += 32) {
      bf16x8 af[4], bfr[4];
      #pragma unroll
      for (int i = 0; i < 4; i++) af[i]  = *(bf16x8*)&As[wm + i * 16 + lm][ks + lk];
      #pragma unroll
      for (int j = 0; j < 4; j++) bfr[j] = *(bf16x8*)&Bs[wn + j * 16 + lm][ks + lk];
      #pragma unroll
      for (int i = 0; i < 4; i++)
        #pragma unroll
        for (int j = 0; j < 4; j++)
          acc[i][j] = __builtin_amdgcn_mfma_f32_16x16x32_bf16(af[i], bfr[j], acc[i][j], 0, 0, 0);
    }
    __syncthreads();
  }
  int r0 = m0 + wm + (lane >> 4) * 4;
  #pragma unroll
  for (int i = 0; i < 4; i++) {
    #pragma unroll
    for (int j = 0; j < 4; j++) {
      int col = n0 + wn + j * 16 + (lane & 15);
      if (col < N) {
        #pragma unroll
        for (int r = 0; r < 4; r++) {
          int row = r0 + i * 16 + r;
          size_t idx = (size_t)row * ldc + col;
          float v = acc[i][j][r];
          if (resid) v += resid[idx];
          if (OUT_F32) ((float*)Cout)[idx] = v;
          else         ((bf16*)Cout)[idx]  = (bf16)v;
        }
      }
    }
  }
}

// ---------------------------------------------------------------- conv1d+SiLU
__global__ __launch_bounds__(256) void conv_silu_kernel(
    const bf16* __restrict__ xbcdt, const float* __restrict__ cw,
    const float* __restrict__ cb, bf16* __restrict__ xc) {
  int idx = blockIdx.x * 256 + threadIdx.x;
  int nC8 = CONV_ / 8;
  if (idx >= BL_ * nC8) return;
  int c8 = idx % nC8, t = idx / nC8;
  int l = t % L_;
  int c = c8 * 8;
  float acc[8];
  f32x4 bv0 = *(const f32x4*)(cb + c);
  f32x4 bv1 = *(const f32x4*)(cb + c + 4);
  #pragma unroll
  for (int q = 0; q < 4; q++) { acc[q] = bv0[q]; acc[4 + q] = bv1[q]; }
  #pragma unroll
  for (int k = 0; k < 4; k++) {
    int ls = l + k - 3;
    if (ls >= 0) {
      const bf16* xp = xbcdt + (size_t)(t + k - 3) * XBCD_ + c;
      bf16x8 xv = *(const bf16x8*)xp;
      f32x4 wv0 = *(const f32x4*)(cw + k * CONV_ + c);
      f32x4 wv1 = *(const f32x4*)(cw + k * CONV_ + c + 4);
      #pragma unroll
      for (int q = 0; q < 4; q++) { acc[q] += (float)xv[q] * wv0[q]; acc[4 + q] += (float)xv[4 + q] * wv1[q]; }
    }
  }
  bf16x8 o;
  #pragma unroll
  for (int q = 0; q < 8; q++) o[q] = (bf16)silu_f(acc[q]);
  *(bf16x8*)(xc + (size_t)t * CONV_ + c) = o;
}

// ---------------------------------------------------------------- dt / dA
__global__ __launch_bounds__(256) void dt_da_kernel(
    const bf16* __restrict__ xbcdt, const float* __restrict__ dt_bias,
    const float* __restrict__ A_log, float* __restrict__ dt, float* __restrict__ dA) {
  int idx = blockIdx.x * 256 + threadIdx.x;
  if (idx >= BL_ * NH) return;
  int h = idx % NH, t = idx / NH;
  float raw = (float)xbcdt[(size_t)t * XBCD_ + CONV_ + h] + dt_bias[h];
  float dtv = (raw > 20.f) ? raw : log1pf(expf(raw));
  dt[idx] = dtv;
  dA[idx] = expf(-expf(A_log[h]) * dtv);
}

// ---------------------------------------------------------------- scan pass 1
// One chunk of 64 timesteps per block. grid 8192: bi = b(1)|c(5)|ph(1)|h(6).
// Starts from h=0, writes y_intra(+Dx) over x-region of xc and the chunk-final
// partial state to Sc[b][c][h][p][n] (bf16).
__global__ __launch_bounds__(256) void scan_chunk_kernel(
    bf16* __restrict__ xc, const float* __restrict__ dt,
    const float* __restrict__ dA, const float* __restrict__ Dp,
    bf16* __restrict__ Sc) {
  __shared__ float xs[64][32];
  __shared__ float Bs[64][64];
  __shared__ float Cs[64][64];
  __shared__ float dAs[64];
  __shared__ float dts[64];
  __shared__ float ys[64][32];
  int bi = blockIdx.x;
  int h = bi & 63, ph = (bi >> 6) & 1, c = (bi >> 7) & 31, b = bi >> 12;
  int p0 = ph * 32;
  int tid = threadIdx.x;
  int nc = tid & 7, pl = tid >> 3;
  float Dv = Dp[h];
  float hst[8] = {};
  size_t rowbase = (size_t)b * L_ + c * 64;
  // ---- stage chunk
  #pragma unroll
  for (int i = 0; i < 8; i++) {
    int idx = tid + i * 256; int s = idx >> 5, pp = idx & 31;
    size_t row = rowbase + s;
    xs[s][pp] = (float)xc[row * CONV_ + h * PD + p0 + pp];
  }
  #pragma unroll
  for (int i = 0; i < 2; i++) {
    int cc = tid + i * 256; int s = cc >> 3, n8 = (cc & 7) * 8;
    size_t row = rowbase + s;
    bf16x8 bv = *(const bf16x8*)(xc + row * CONV_ + DI_ + n8);
    bf16x8 cv = *(const bf16x8*)(xc + row * CONV_ + DI_ + NST + n8);
    #pragma unroll
    for (int q = 0; q < 8; q++) { Bs[s][n8 + q] = (float)bv[q]; Cs[s][n8 + q] = (float)cv[q]; }
  }
  if (tid < 64) {
    size_t row = rowbase + tid;
    dAs[tid] = dA[row * NH + h];
    dts[tid] = dt[row * NH + h];
  }
  __syncthreads();
  // ---- serial 64 steps
  for (int s = 0; s < 64; s++) {
    float dAv = dAs[s];
    float xv  = xs[s][pl];
    float dtx = dts[s] * xv;
    f32x4 Bv0 = *(f32x4*)&Bs[s][nc * 8];
    f32x4 Bv1 = *(f32x4*)&Bs[s][nc * 8 + 4];
    f32x4 Cv0 = *(f32x4*)&Cs[s][nc * 8];
    f32x4 Cv1 = *(f32x4*)&Cs[s][nc * 8 + 4];
    float yp = 0.f;
    #pragma unroll
    for (int q = 0; q < 4; q++) { hst[q]     = dAv * hst[q]     + dtx * Bv0[q]; yp += hst[q]     * Cv0[q]; }
    #pragma unroll
    for (int q = 0; q < 4; q++) { hst[4 + q] = dAv * hst[4 + q] + dtx * Bv1[q]; yp += hst[4 + q] * Cv1[q]; }
    yp += __shfl_xor(yp, 1, 64);
    yp += __shfl_xor(yp, 2, 64);
    yp += __shfl_xor(yp, 4, 64);
    if (nc == 0) ys[s][pl] = yp + Dv * xv;
  }
  __syncthreads();
  // ---- write y_intra and partial state
  #pragma unroll
  for (int i = 0; i < 8; i++) {
    int idx = tid + i * 256; int s = idx >> 5, pp = idx & 31;
    xc[(rowbase + s) * CONV_ + h * PD + p0 + pp] = (bf16)ys[s][pp];
  }
  bf16* scp = Sc + ((((size_t)b * NCHUNK + c) * NH + h) << 12) + (p0 + pl) * 64 + nc * 8;
  bf16x8 so;
  #pragma unroll
  for (int q = 0; q < 8; q++) so[q] = (bf16)hst[q];
  *(bf16x8*)scp = so;
}

// ---------------------------------------------------------------- scan pass 2
// 128 blocks (b,h). Sequential over 32 chunks; replaces Sc[b][c][h] in-place
// with h_prev (state BEFORE chunk c). Atot = exp(-aA * sum_chunk dt).
__global__ __launch_bounds__(256) void state_scan_kernel(
    bf16* __restrict__ Sc, const float* __restrict__ dt,
    const float* __restrict__ A_log) {
  __shared__ float sdts[64];
  int b = blockIdx.x >> 6, h = blockIdx.x & 63;
  int tid = threadIdx.x;
  float aA = expf(A_log[h]);
  float H[16] = {};
  for (int c = 0; c < NCHUNK; c++) {
    if (tid < 64) sdts[tid] = dt[((size_t)b * L_ + c * 64 + tid) * NH + h];
    __syncthreads();
    float sum = 0.f;
    #pragma unroll 8
    for (int i = 0; i < 64; i++) sum += sdts[i];
    float Atot = expf(-aA * sum);
    bf16* p = Sc + ((((size_t)b * NCHUNK + c) * NH + h) << 12) + tid * 16;
    bf16x8 s0 = *(bf16x8*)p;
    bf16x8 s1 = *(bf16x8*)(p + 8);
    bf16x8 o0, o1;
    #pragma unroll
    for (int q = 0; q < 8; q++) {
      float n0 = Atot * H[q]     + (float)s0[q];
      float n1 = Atot * H[8 + q] + (float)s1[q];
      o0[q] = (bf16)H[q]; o1[q] = (bf16)H[8 + q];   // h_prev for chunk c
      H[q] = n0; H[8 + q] = n1;
    }
    *(bf16x8*)p = o0;
    *(bf16x8*)(p + 8) = o1;
    __syncthreads();
  }
}

// ---------------------------------------------------------------- scan pass 3
// grid 8192 (same encode as pass1): y[s][p] += exp(-aA*cumdt_s) * C_s · h_prev[p].
__global__ __launch_bounds__(256) void y_inter_kernel(
    bf16* __restrict__ xc, const float* __restrict__ dt,
    const float* __restrict__ A_log, const bf16* __restrict__ Sc) {
  __shared__ float hp[32][64];
  __shared__ float Cs[64][64];
  __shared__ float sdts[64];
  __shared__ float expA[64];
  __shared__ float ys[64][32];
  int bi = blockIdx.x;
  int h = bi & 63, ph = (bi >> 6) & 1, c = (bi >> 7) & 31, b = bi >> 12;
  int p0 = ph * 32;
  int tid = threadIdx.x;
  int nc = tid & 7, pl = tid >> 3;
  float aA = expf(A_log[h]);
  size_t rowbase = (size_t)b * L_ + c * 64;
  // stage h_prev (32 rows of this p-half)
  const bf16* scp = Sc + ((((size_t)b * NCHUNK + c) * NH + h) << 12);
  {
    int idx = tid * 8; int pp = idx >> 6, nn = idx & 63;
    bf16x8 hv = *(const bf16x8*)(scp + (p0 + pp) * 64 + nn);
    #pragma unroll
    for (int q = 0; q < 8; q++) hp[pp][nn + q] = (float)hv[q];
  }
  if (tid < 64) sdts[tid] = dt[(rowbase + tid) * NH + h];
  __syncthreads();
  if (tid < 64) {
    float cum = 0.f;
    for (int i = 0; i <= tid; i++) cum += sdts[i];
    expA[tid] = expf(-aA * cum);
  }
  __syncthreads();
  // stage C scaled by expA[s]
  #pragma unroll
  for (int i = 0; i < 2; i++) {
    int cc = tid + i * 256; int s = cc >> 3, n8 = (cc & 7) * 8;
    bf16x8 cv = *(const bf16x8*)(xc + (rowbase + s) * CONV_ + DI_ + NST + n8);
    float e = expA[s];
    #pragma unroll
    for (int q = 0; q < 8; q++) Cs[s][n8 + q] = e * (float)cv[q];
  }
  __syncthreads();
  float hr[8];
  #pragma unroll
  for (int q = 0; q < 8; q++) hr[q] = hp[pl][nc * 8 + q];
  for (int s = 0; s < 64; s++) {
    f32x4 Cv0 = *(f32x4*)&Cs[s][nc * 8];
    f32x4 Cv1 = *(f32x4*)&Cs[s][nc * 8 + 4];
    float yp = 0.f;
    #pragma unroll
    for (int q = 0; q < 4; q++) yp += hr[q] * Cv0[q];
    #pragma unroll
    for (int q = 0; q < 4; q++) yp += hr[4 + q] * Cv1[q];
    yp += __shfl_xor(yp, 1, 64);
    yp += __shfl_xor(yp, 2, 64);
    yp += __shfl_xor(yp, 4, 64);
    if (nc == 0) ys[s][pl] = yp;
  }
  __syncthreads();
  // accumulate into y (x-region of xc)
  #pragma unroll
  for (int i = 0; i < 8; i++) {
    int idx = tid + i * 256; int s = idx >> 5, pp = idx & 31;
    size_t gi = (rowbase + s) * CONV_ + h * PD + p0 + pp;
    xc[gi] = (bf16)((float)xc[gi] + ys[s][pp]);
  }
}

// ---------------------------------------------------------------- gated RMSNorm
__global__ __launch_bounds__(256) void gated_norm_kernel(
    const bf16* __restrict__ xc, bf16* __restrict__ zbuf,
    const float* __restrict__ nw) {
  int t = blockIdx.x;
  int base = threadIdx.x * 16;
  const bf16* yr = xc + (size_t)t * CONV_;
  bf16* zr = zbuf + (size_t)t * DI_;
  float tv[16], ss = 0.f;
  #pragma unroll
  for (int i8 = 0; i8 < 2; i8++) {
    bf16x8 yv = *(const bf16x8*)(yr + base + i8 * 8);
    bf16x8 zv = *(const bf16x8*)(zr + base + i8 * 8);
    #pragma unroll
    for (int q = 0; q < 8; q++) {
      float tt = (float)yv[q] * silu_f((float)zv[q]);
      tv[i8 * 8 + q] = tt;
      ss += tt * tt;
    }
  }
  ss = block_reduce_sum_256(ss);
  float r = rsqrtf(ss / (float)DI_ + EPS_);
  #pragma unroll
  for (int i8 = 0; i8 < 2; i8++) {
    f32x4 w0 = *(const f32x4*)(nw + base + i8 * 8);
    f32x4 w1 = *(const f32x4*)(nw + base + i8 * 8 + 4);
    bf16x8 o;
    #pragma unroll
    for (int q = 0; q < 4; q++) {
      o[q]     = (bf16)(w0[q] * tv[i8 * 8 + q] * r);
      o[4 + q] = (bf16)(w1[q] * tv[i8 * 8 + 4 + q] * r);
    }
    *(bf16x8*)(zr + base + i8 * 8) = o;
  }
}

// ---------------------------------------------------------------- ws diagnostic
__global__ void ws_report_kernel(float* out, float ws_mb) {
  if (blockIdx.x == 0 && threadIdx.x == 0) out[0] = ws_mb;
}

// ---------------------------------------------------------------- launch
extern "C" void kernel_launch(void* const* d_in, const int* in_sizes, int n_in,
                              void* d_out, int out_size, void* d_ws, size_t ws_size,
                              hipStream_t stream) {
  const float* u        = (const float*)d_in[0];
  const float* ln_w     = (const float*)d_in[1];
  const float* in_proj  = (const float*)d_in[2];
  const float* conv_w   = (const float*)d_in[3];
  const float* conv_b   = (const float*)d_in[4];
  const float* dt_bias  = (const float*)d_in[5];
  const float* A_log    = (const float*)d_in[6];
  const float* Dp       = (const float*)d_in[7];
  const float* norm_w   = (const float*)d_in[8];
  const float* out_proj = (const float*)d_in[9];
  float* out = (float*)d_out;

  bf16* hs = (bf16*)d_out;     // scratch inside d_out (dead before final GEMM)

  char* ws = (char*)d_ws;
  size_t off = 0;
  auto alloc = [&](size_t bytes) { char* p = ws + off; off = (off + bytes + 255) & ~(size_t)255; return p; };
  float* dt   = (float*)alloc((size_t)BL_ * NH * 4);          //  1.05 MB
  float* dA   = (float*)alloc((size_t)BL_ * NH * 4);          //  1.05 MB
  bf16*  shbuf= (bf16*)alloc((size_t)BL_ * XBCD_ * 2);        // 35.1 MB (xbcdt → Sc → zbuf)
  bf16*  xc   = (bf16*)alloc((size_t)BL_ * CONV_ * 2);        // 34.6 MB
  size_t need = off;                                          // ~71.9 MB

  if (ws_size < need) {
    ws_report_kernel<<<1, 64, 0, stream>>>(out, (float)(ws_size >> 20));
    return;
  }

  bf16* xbcdt = shbuf;          // phase 1: BL x XBCD_
  bf16* Sc    = shbuf;          // phase 2: [b][c][h][64][64] bf16 = 32 MB
  bf16* zbuf  = shbuf;          // phase 3: BL x DI_

  rmsnorm_in_kernel<<<BL_, 256, 0, stream>>>(u, ln_w, hs);
  gemm_nt_kernel<false><<<dim3((XBCD_ + 127) / 128, BL_ / 128), 256, 0, stream>>>(
      hs, DM_, in_proj + (size_t)DI_ * DM_, xbcdt, XBCD_, nullptr, XBCD_, DM_);
  conv_silu_kernel<<<(BL_ * (CONV_ / 8) + 255) / 256, 256, 0, stream>>>(
      xbcdt, conv_w, conv_b, xc);
  dt_da_kernel<<<(BL_ * NH + 255) / 256, 256, 0, stream>>>(
      xbcdt, dt_bias, A_log, dt, dA);
  // chunked scan (xbcdt dead from here; shbuf becomes Sc)
  scan_chunk_kernel<<<B_ * NH * NCHUNK * 2, 256, 0, stream>>>(xc, dt, dA, Dp, Sc);
  state_scan_kernel<<<B_ * NH, 256, 0, stream>>>(Sc, dt, A_log);
  y_inter_kernel<<<B_ * NH * NCHUNK * 2, 256, 0, stream>>>(xc, dt, A_log, Sc);
  // z part of in_proj (Sc dead; shbuf becomes zbuf)
  gemm_nt_kernel<false><<<dim3(DI_ / 128, BL_ / 128), 256, 0, stream>>>(
      hs, DM_, in_proj, zbuf, DI_, nullptr, DI_, DM_);
  gated_norm_kernel<<<BL_, 256, 0, stream>>>(xc, zbuf, norm_w);
  gemm_nt_kernel<true><<<dim3(DM_ / 128, BL_ / 128), 256, 0, stream>>>(
      zbuf, DI_, out_proj, out, DM_, u, DM_, DI_);
}